// Round 5
// baseline (6195.190 us; speedup 1.0000x reference)
//
#include <hip/hip_runtime.h>
#include <cfloat>
#include <cstdint>
#include <cstddef>

#define NTOK 8192
#define NE   8192
#define DIM  512
#define OUT0 4194304   // floats in x_q_st region

// ---------------- fp64 exp, branchless, |x| <= ~482*ln2 ----------------
__device__ __forceinline__ double fexp_d(double x){
  const double L2E = 1.4426950408889634074;
  const double LN2 = 0.69314718055994530942;
  double kd = rint(x * L2E);
  double r  = fma(-kd, LN2, x);                 // |r| <= 0.3466
  double p = 2.4801587301587301566e-05;         // 1/8!
  p = fma(p, r, 1.9841269841269841253e-04);     // 1/7!
  p = fma(p, r, 1.3888888888888889419e-03);     // 1/6!
  p = fma(p, r, 8.3333333333333332177e-03);     // 1/5!
  p = fma(p, r, 4.1666666666666664354e-02);     // 1/4!
  p = fma(p, r, 1.6666666666666665741e-01);     // 1/3!
  p = fma(p, r, 5.0e-01);
  p = fma(p, r, 1.0);
  p = fma(p, r, 1.0);
  long long eb = ((long long)(1023 + (int)kd)) << 52;
  return p * __longlong_as_double(eb);
}

__device__ __forceinline__ unsigned int f2ord(float f){
  unsigned int u = __float_as_uint(f);
  return (u & 0x80000000u) ? ~u : (u | 0x80000000u);
}
__device__ __forceinline__ float ord2f(unsigned int v){
  unsigned int u = (v & 0x80000000u) ? (v ^ 0x80000000u) : ~v;
  return __uint_as_float(u);
}

// ---------------- numpy pairwise sum of squares (exact order) ----------------
__device__ float pw128_sq(const float* __restrict__ p){
  float r[8];
#pragma unroll
  for (int j = 0; j < 8; ++j) r[j] = __fmul_rn(p[j], p[j]);
#pragma unroll
  for (int i = 8; i < 128; i += 8)
#pragma unroll
    for (int j = 0; j < 8; ++j) r[j] = __fadd_rn(r[j], __fmul_rn(p[i+j], p[i+j]));
  float s01 = __fadd_rn(r[0], r[1]), s23 = __fadd_rn(r[2], r[3]);
  float s45 = __fadd_rn(r[4], r[5]), s67 = __fadd_rn(r[6], r[7]);
  return __fadd_rn(__fadd_rn(s01, s23), __fadd_rn(s45, s67));
}
__device__ float pw512_sq(const float* __restrict__ p){
  float s0 = __fadd_rn(pw128_sq(p),       pw128_sq(p + 128));
  float s1 = __fadd_rn(pw128_sq(p + 256), pw128_sq(p + 384));
  return __fadd_rn(s0, s1);
}

// blocks 0..31 -> X norms, 32..63 -> E norms
__global__ __launch_bounds__(256) void normsK(const float* __restrict__ X, const float* __restrict__ E,
    float* __restrict__ avec, float* __restrict__ hvec){
  int blk = blockIdx.x;
  int i = (blk & 31) * 256 + threadIdx.x;
  if (blk < 32) avec[i] = pw512_sq(X + (size_t)i * DIM);
  else          hvec[i] = pw512_sq(E + (size_t)i * DIM);
}

__global__ void initK(unsigned int* sc32){
  if (threadIdx.x == 0){ sc32[0] = 0u; sc32[1] = 0xFFFFFFFFu; }
}

__global__ void finalizeK(const unsigned int* sc32, float* scf){
  if (threadIdx.x == 0){
    float mx = ord2f(sc32[0]);
    float mn = ord2f(sc32[1]);
    float middle = __fmul_rn(__fadd_rn(mx, mn), 0.5f);
    float amp    = __fadd_rn(__fsub_rn(mx, middle), 1e-5f);
    scf[0] = middle; scf[1] = amp;
  }
}

__global__ void diagK(float* __restrict__ out, int n, float tag){
  int i = blockIdx.x * blockDim.x + threadIdx.x;
  int stride = gridDim.x * blockDim.x;
  for (; i < n; i += stride) out[i] = (i == OUT0) ? tag : 0.f;
}

// ---------------- fp32 GEMM 128x128x16, 8x8/thread (split 4+4), k-ascending FMA ----------------
// BK=16: staging write banks = (16*(l&3 pairs) + (l>>2 spans 16) + 4j) -> exact 2-way (free).
// Reads: As base ty*4 -> 4 addrs x16-lane bcast, conflict-free; Bs base tx*4 -> 2-way (free).
#define GBM 128
#define GBN 128
#define GBK 16
#define GLDT 132
__global__ __launch_bounds__(256, 6) void gemm128(const float* __restrict__ X, const float* __restrict__ E,
    const float* __restrict__ avec, const float* __restrict__ hvec,
    float* __restrict__ dmat, unsigned int* __restrict__ sc32){
  __shared__ float As[GBK][GLDT];
  __shared__ float Bs[GBK][GLDT];
  __shared__ float red[256];
  int tid = threadIdx.x;
  int tx = tid & 15, ty = tid >> 4;
  int bm = blockIdx.y * GBM, bn = blockIdx.x * GBN;

  float acc[2][4][2][4];
#pragma unroll
  for (int ih = 0; ih < 2; ++ih)
#pragma unroll
    for (int i = 0; i < 4; ++i)
#pragma unroll
      for (int jh = 0; jh < 2; ++jh)
#pragma unroll
        for (int j = 0; j < 4; ++j) acc[ih][i][jh][j] = 0.f;

  for (int kt = 0; kt < DIM; kt += GBK){
#pragma unroll
    for (int s = 0; s < 2; ++s){
      int flat = tid + s * 256;          // 0..511
      int m  = flat >> 2;                // 0..127
      int k4 = (flat & 3) * 4;           // 0,4,8,12
      float4 va = *(const float4*)(X + (size_t)(bm + m) * DIM + kt + k4);
      As[k4+0][m] = va.x; As[k4+1][m] = va.y; As[k4+2][m] = va.z; As[k4+3][m] = va.w;
      float4 vb = *(const float4*)(E + (size_t)(bn + m) * DIM + kt + k4);
      Bs[k4+0][m] = vb.x; Bs[k4+1][m] = vb.y; Bs[k4+2][m] = vb.z; Bs[k4+3][m] = vb.w;
    }
    __syncthreads();
#pragma unroll
    for (int kk = 0; kk < GBK; ++kk){
      float a[2][4], b[2][4];
      *(float4*)a[0] = *(const float4*)&As[kk][ty * 4];
      *(float4*)a[1] = *(const float4*)&As[kk][64 + ty * 4];
      *(float4*)b[0] = *(const float4*)&Bs[kk][tx * 4];
      *(float4*)b[1] = *(const float4*)&Bs[kk][64 + tx * 4];
#pragma unroll
      for (int ih = 0; ih < 2; ++ih)
#pragma unroll
        for (int i = 0; i < 4; ++i)
#pragma unroll
          for (int jh = 0; jh < 2; ++jh)
#pragma unroll
            for (int j = 0; j < 4; ++j)
              acc[ih][i][jh][j] = fmaf(a[ih][i], b[jh][j], acc[ih][i][jh][j]);
    }
    __syncthreads();
  }

  float lmax = -FLT_MAX, lmin = FLT_MAX;
#pragma unroll
  for (int ih = 0; ih < 2; ++ih){
#pragma unroll
    for (int i = 0; i < 4; ++i){
      int gr = bm + ih * 64 + ty * 4 + i;
      float a = avec[gr];
#pragma unroll
      for (int jh = 0; jh < 2; ++jh){
        float dv[4];
#pragma unroll
        for (int j = 0; j < 4; ++j){
          int gc = bn + jh * 64 + tx * 4 + j;
          float t = __fadd_rn(a, hvec[gc]);                  // fl(a_b + h_k)
          float d = __fsub_rn(t, 2.0f * acc[ih][i][jh][j]);  // fl(t - 2c)
          dv[j] = d;
          lmax = fmaxf(lmax, d); lmin = fminf(lmin, d);
        }
        *(float4*)(dmat + (size_t)gr * NE + bn + jh * 64 + tx * 4) = *(float4*)&dv[0];
      }
    }
  }
  red[tid] = lmax; __syncthreads();
  for (int s = 128; s > 0; s >>= 1){ if (tid < s) red[tid] = fmaxf(red[tid], red[tid+s]); __syncthreads(); }
  float bmax = red[0];
  __syncthreads();
  red[tid] = lmin; __syncthreads();
  for (int s = 128; s > 0; s >>= 1){ if (tid < s) red[tid] = fminf(red[tid], red[tid+s]); __syncthreads(); }
  if (tid == 0){
    atomicMax(&sc32[0], f2ord(bmax));
    atomicMin(&sc32[1], f2ord(red[0]));
  }
}

// ---------------- Sinkhorn sweeps ----------------
#define EXPD(x) fexp_d((double)__fdiv_rn(__fsub_rn((x), middle), amp) * NIE)

// row step: r_k = sum_b exp(L[b,k]) * w_b ; per-k fp64 chain ascending bb within chunk.
// grid (16, 64): 1024 blocks (4/CU) — TLP restored; 128-row chunks (fp64 reassoc only, safe)
__global__ __launch_bounds__(256) void rowPassK(const float* __restrict__ dmat, const double* __restrict__ wvec,
    const float* __restrict__ scf, double* __restrict__ partials){
  int tid = threadIdx.x;
  int k0 = blockIdx.x * 512 + tid * 2;
  int b0 = blockIdx.y * 128;
  float middle = scf[0], amp = scf[1];
  const double NIE = -(1.0 / 0.003);
  const float* p = dmat + (size_t)b0 * NE + k0;
  double a0 = 0.0, a1 = 0.0;
  if (wvec){
    for (int bb = 0; bb < 128; bb += 2){
      float2 v0 = *(const float2*)(p + (size_t)(bb+0) * NE);
      float2 v1 = *(const float2*)(p + (size_t)(bb+1) * NE);
      double w0 = wvec[b0+bb+0], w1 = wvec[b0+bb+1];
      a0 = fma(EXPD(v0.x), w0, a0); a1 = fma(EXPD(v0.y), w0, a1);
      a0 = fma(EXPD(v1.x), w1, a0); a1 = fma(EXPD(v1.y), w1, a1);
    }
  } else {
    for (int bb = 0; bb < 128; bb += 2){
      float2 v0 = *(const float2*)(p + (size_t)(bb+0) * NE);
      float2 v1 = *(const float2*)(p + (size_t)(bb+1) * NE);
      a0 += EXPD(v0.x); a1 += EXPD(v0.y);
      a0 += EXPD(v1.x); a1 += EXPD(v1.y);
    }
  }
  double* q = partials + (size_t)blockIdx.y * NE + k0;
  q[0] = a0; q[1] = a1;
}

__global__ void reduceAK(const double* __restrict__ partials, double* __restrict__ ak){
  int k = blockIdx.x * 256 + threadIdx.x;
  double s = 0.0;
  for (int c = 0; c < 64; ++c) s += partials[(size_t)c * NE + k];
  ak[k] = 1.0 / (8192.0 * s);
}

// col step: per-thread chain k = tid, tid+256, ... ascending (bit-exact)
__global__ __launch_bounds__(256) void colPassK(const float* __restrict__ dmat, const double* __restrict__ ak,
    const float* __restrict__ scf, double* __restrict__ bvec){
  __shared__ double sd[256];
  int b = blockIdx.x, tid = threadIdx.x;
  float middle = scf[0], amp = scf[1];
  const double NIE = -(1.0 / 0.003);
  const float* row = dmat + (size_t)b * NE;
  double acc = 0.0;
  for (int kb = 0; kb < 32; kb += 4){
    int k0 = tid + (kb+0) * 256, k1 = tid + (kb+1) * 256, k2 = tid + (kb+2) * 256, k3 = tid + (kb+3) * 256;
    float r0 = row[k0], r1 = row[k1], r2 = row[k2], r3 = row[k3];
    double q0 = ak[k0], q1 = ak[k1], q2 = ak[k2], q3 = ak[k3];
    acc = fma(EXPD(r0), q0, acc);
    acc = fma(EXPD(r1), q1, acc);
    acc = fma(EXPD(r2), q2, acc);
    acc = fma(EXPD(r3), q3, acc);
  }
  sd[tid] = acc; __syncthreads();
  for (int s = 128; s > 0; s >>= 1){ if (tid < s) sd[tid] += sd[tid+s]; __syncthreads(); }
  if (tid == 0) bvec[b] = 1.0 / (8192.0 * sd[0]);
}

__global__ void lnaK(const double* __restrict__ ak, double* __restrict__ lna){
  int k = blockIdx.x * 256 + threadIdx.x;
  lna[k] = log(ak[k]);
}

// argmax_k [ ln a_k + L[b,k] ] fused with loss partial for the token
__global__ __launch_bounds__(256) void argmaxLossK(const float* __restrict__ dmat, const double* __restrict__ lna,
    const float* __restrict__ scf, const float* __restrict__ X, const float* __restrict__ E,
    float* __restrict__ idxF, double* __restrict__ lparts){
  __shared__ double sv[256];
  __shared__ int    si[256];
  __shared__ int    sidx;
  int b = blockIdx.x, tid = threadIdx.x;
  float middle = scf[0], amp = scf[1];
  const double NIE = -(1.0 / 0.003);
  const float* row = dmat + (size_t)b * NE;
  double best = -1.0e300; int bk = NE;
#pragma unroll 2
  for (int c = 0; c < 8; ++c){
    int k = c * 1024 + tid * 4;
    float4 v = *(const float4*)(row + k);
    double l0 = lna[k], l1 = lna[k+1], l2 = lna[k+2], l3 = lna[k+3];
    double t0 = fma((double)__fdiv_rn(__fsub_rn(v.x, middle), amp), NIE, l0);
    double t1 = fma((double)__fdiv_rn(__fsub_rn(v.y, middle), amp), NIE, l1);
    double t2 = fma((double)__fdiv_rn(__fsub_rn(v.z, middle), amp), NIE, l2);
    double t3 = fma((double)__fdiv_rn(__fsub_rn(v.w, middle), amp), NIE, l3);
    if (t0 > best){ best = t0; bk = k; }
    if (t1 > best){ best = t1; bk = k+1; }
    if (t2 > best){ best = t2; bk = k+2; }
    if (t3 > best){ best = t3; bk = k+3; }
  }
  sv[tid] = best; si[tid] = bk; __syncthreads();
  for (int s = 128; s > 0; s >>= 1){
    if (tid < s){
      double o = sv[tid+s]; int ok = si[tid+s];
      if (o > sv[tid] || (o == sv[tid] && ok < si[tid])){ sv[tid] = o; si[tid] = ok; }
    }
    __syncthreads();
  }
  if (tid == 0){ idxF[b] = (float)si[0]; sidx = si[0]; }
  __syncthreads();

  // fused loss partial
  int id = sidx;
  const float* xr = X + (size_t)b * DIM;
  const float* er = E + (size_t)id * DIM;
  double ls = 0.0;
#pragma unroll
  for (int c = 0; c < 2; ++c){
    int dpos = tid + c * 256;
    float diff = __fsub_rn(er[dpos], xr[dpos]);
    ls = fma((double)diff, (double)diff, ls);
  }
  sv[tid] = ls; __syncthreads();
  for (int s = 128; s > 0; s >>= 1){ if (tid < s) sv[tid] += sv[tid+s]; __syncthreads(); }
  if (tid == 0) lparts[b] = sv[0];
}

__global__ __launch_bounds__(256) void lossFinK(const double* __restrict__ lparts, float* __restrict__ lossOut){
  __shared__ double sd[256];
  int tid = threadIdx.x;
  double s = 0.0;
  for (int b = tid; b < NTOK; b += 256) s += lparts[b];
  sd[tid] = s; __syncthreads();
  for (int st = 128; st > 0; st >>= 1){ if (tid < st) sd[tid] += sd[tid+st]; __syncthreads(); }
  if (tid == 0){
    double v = sd[0] / (double)((size_t)NTOK * DIM);
    float vf = (float)v;
    lossOut[0] = __fadd_rn(vf, __fmul_rn(0.25f, vf));
  }
}

__global__ __launch_bounds__(256) void out0K(const float* __restrict__ X, const float* __restrict__ E,
    const float* __restrict__ idxF, float* __restrict__ out0){
  int b = blockIdx.x, tid = threadIdx.x;
  int id = (int)idxF[b];
  const float* xr = X + (size_t)b * DIM;
  const float* er = E + (size_t)id * DIM;
#pragma unroll
  for (int c = 0; c < 2; ++c){
    int dpos = tid + c * 256;
    float xv = xr[dpos];
    float diff = __fsub_rn(er[dpos], xv);
    out0[(size_t)b * DIM + dpos] = __fadd_rn(xv, diff);
  }
}

extern "C" void kernel_launch(void* const* d_in, const int* in_sizes, int n_in,
                              void* d_out, int out_size, void* d_ws, size_t ws_size,
                              hipStream_t stream){
  (void)in_sizes; (void)n_in;
  const float* X = (const float*)d_in[0];
  const float* E = (const float*)d_in[1];
  float* out = (float*)d_out;

  if (ws_size < 268435456ull || d_ws == nullptr){
    diagK<<<2048, 256, 0, stream>>>(out, out_size, (float)(ws_size >> 20));
    return;
  }
  float* dmat = (float*)d_ws;

  // Small scratch lives in the x_q_st region of d_out (rewritten by out0K last).
  float*  avec   = out;                              // 8192 f
  float*  hvec   = out + 8192;                       // 8192 f
  double* parts  = (double*)(out + 16384);           // 64*8192 doubles (4 MB)
  double* ak     = (double*)(out + 1064960);         // 8192 d
  double* bvec   = (double*)(out + 1081344);         // 8192 d
  double* lna    = (double*)(out + 1097728);         // 8192 d
  unsigned int* sc32 = (unsigned int*)(out + 1114112);
  float*  scf    = out + 1114114;
  double* lparts = parts;

  float* out0    = out;
  float* lossOut = out + OUT0;
  float* idxF    = out + OUT0 + 1;

  initK<<<1, 64, 0, stream>>>(sc32);
  normsK<<<64, 256, 0, stream>>>(X, E, avec, hvec);

  dim3 gg(NE / GBN, NTOK / GBM);
  gemm128<<<gg, 256, 0, stream>>>(X, E, avec, hvec, dmat, sc32);
  finalizeK<<<1, 64, 0, stream>>>(sc32, scf);

  dim3 rp(16, 64);
  rowPassK<<<rp, 256, 0, stream>>>(dmat, nullptr, scf, parts);
  reduceAK<<<32, 256, 0, stream>>>(parts, ak);
  for (int it = 0; it < 4; ++it){
    colPassK<<<NTOK, 256, 0, stream>>>(dmat, ak, scf, bvec);
    rowPassK<<<rp, 256, 0, stream>>>(dmat, bvec, scf, parts);
    reduceAK<<<32, 256, 0, stream>>>(parts, ak);
  }
  // 5th col step is a per-token positive scale -> argmax invariant -> skipped

  lnaK<<<32, 256, 0, stream>>>(ak, lna);
  argmaxLossK<<<NTOK, 256, 0, stream>>>(dmat, lna, scf, X, E, idxF, lparts);
  lossFinK<<<1, 256, 0, stream>>>(lparts, lossOut);
  out0K<<<NTOK, 256, 0, stream>>>(X, E, idxF, out0);
}

// Round 6
// 1500.161 us; speedup vs baseline: 4.1297x; 4.1297x over previous
//
#include <hip/hip_runtime.h>
#include <cfloat>
#include <cstdint>
#include <cstddef>

#define NTOK 8192
#define NE   8192
#define DIM  512
#define OUT0 4194304   // floats in x_q_st region

// ---------------- fp64 exp, branchless, |x| <= ~482*ln2 ----------------
__device__ __forceinline__ double fexp_d(double x){
  const double L2E = 1.4426950408889634074;
  const double LN2 = 0.69314718055994530942;
  double kd = rint(x * L2E);
  double r  = fma(-kd, LN2, x);                 // |r| <= 0.3466
  double p = 2.4801587301587301566e-05;         // 1/8!
  p = fma(p, r, 1.9841269841269841253e-04);     // 1/7!
  p = fma(p, r, 1.3888888888888889419e-03);     // 1/6!
  p = fma(p, r, 8.3333333333333332177e-03);     // 1/5!
  p = fma(p, r, 4.1666666666666664354e-02);     // 1/4!
  p = fma(p, r, 1.6666666666666665741e-01);     // 1/3!
  p = fma(p, r, 5.0e-01);
  p = fma(p, r, 1.0);
  p = fma(p, r, 1.0);
  long long eb = ((long long)(1023 + (int)kd)) << 52;
  return p * __longlong_as_double(eb);
}

__device__ __forceinline__ unsigned int f2ord(float f){
  unsigned int u = __float_as_uint(f);
  return (u & 0x80000000u) ? ~u : (u | 0x80000000u);
}
__device__ __forceinline__ float ord2f(unsigned int v){
  unsigned int u = (v & 0x80000000u) ? (v ^ 0x80000000u) : ~v;
  return __uint_as_float(u);
}

// ---------------- numpy pairwise sum of squares (exact order) ----------------
__device__ float pw128_sq(const float* __restrict__ p){
  float r[8];
#pragma unroll
  for (int j = 0; j < 8; ++j) r[j] = __fmul_rn(p[j], p[j]);
#pragma unroll
  for (int i = 8; i < 128; i += 8)
#pragma unroll
    for (int j = 0; j < 8; ++j) r[j] = __fadd_rn(r[j], __fmul_rn(p[i+j], p[i+j]));
  float s01 = __fadd_rn(r[0], r[1]), s23 = __fadd_rn(r[2], r[3]);
  float s45 = __fadd_rn(r[4], r[5]), s67 = __fadd_rn(r[6], r[7]);
  return __fadd_rn(__fadd_rn(s01, s23), __fadd_rn(s45, s67));
}
__device__ float pw512_sq(const float* __restrict__ p){
  float s0 = __fadd_rn(pw128_sq(p),       pw128_sq(p + 128));
  float s1 = __fadd_rn(pw128_sq(p + 256), pw128_sq(p + 384));
  return __fadd_rn(s0, s1);
}

// blocks 0..31 -> X norms, 32..63 -> E norms
__global__ __launch_bounds__(256) void normsK(const float* __restrict__ X, const float* __restrict__ E,
    float* __restrict__ avec, float* __restrict__ hvec){
  int blk = blockIdx.x;
  int i = (blk & 31) * 256 + threadIdx.x;
  if (blk < 32) avec[i] = pw512_sq(X + (size_t)i * DIM);
  else          hvec[i] = pw512_sq(E + (size_t)i * DIM);
}

__global__ void initK(unsigned int* sc32){
  if (threadIdx.x == 0){ sc32[0] = 0u; sc32[1] = 0xFFFFFFFFu; }
}

__global__ void finalizeK(const unsigned int* sc32, float* scf){
  if (threadIdx.x == 0){
    float mx = ord2f(sc32[0]);
    float mn = ord2f(sc32[1]);
    float middle = __fmul_rn(__fadd_rn(mx, mn), 0.5f);
    float amp    = __fadd_rn(__fsub_rn(mx, middle), 1e-5f);
    scf[0] = middle; scf[1] = amp;
  }
}

__global__ void diagK(float* __restrict__ out, int n, float tag){
  int i = blockIdx.x * blockDim.x + threadIdx.x;
  int stride = gridDim.x * blockDim.x;
  for (; i < n; i += stride) out[i] = (i == OUT0) ? tag : 0.f;
}

// ---------------- fp32 GEMM 128x128x16, 8x8/thread (split 4+4), k-ascending FMA ----------------
// BK=16 staging: write banks exact 2-way (free). Reads: As bcast conflict-free, Bs 2-way (free).
// launch_bounds(256,4): 128 VGPR cap — fits 64 acc + 16 a/b + addressing, NO spill
// (256,6 capped at 85 VGPR -> acc spilled to scratch -> 23 GB HBM traffic, 8x regression).
#define GBM 128
#define GBN 128
#define GBK 16
#define GLDT 132
__global__ __launch_bounds__(256, 4) void gemm128(const float* __restrict__ X, const float* __restrict__ E,
    const float* __restrict__ avec, const float* __restrict__ hvec,
    float* __restrict__ dmat, unsigned int* __restrict__ sc32){
  __shared__ float As[GBK][GLDT];
  __shared__ float Bs[GBK][GLDT];
  __shared__ float red[256];
  int tid = threadIdx.x;
  int tx = tid & 15, ty = tid >> 4;
  int bm = blockIdx.y * GBM, bn = blockIdx.x * GBN;

  float acc[2][4][2][4];
#pragma unroll
  for (int ih = 0; ih < 2; ++ih)
#pragma unroll
    for (int i = 0; i < 4; ++i)
#pragma unroll
      for (int jh = 0; jh < 2; ++jh)
#pragma unroll
        for (int j = 0; j < 4; ++j) acc[ih][i][jh][j] = 0.f;

  for (int kt = 0; kt < DIM; kt += GBK){
#pragma unroll
    for (int s = 0; s < 2; ++s){
      int flat = tid + s * 256;          // 0..511
      int m  = flat >> 2;                // 0..127
      int k4 = (flat & 3) * 4;           // 0,4,8,12
      float4 va = *(const float4*)(X + (size_t)(bm + m) * DIM + kt + k4);
      As[k4+0][m] = va.x; As[k4+1][m] = va.y; As[k4+2][m] = va.z; As[k4+3][m] = va.w;
      float4 vb = *(const float4*)(E + (size_t)(bn + m) * DIM + kt + k4);
      Bs[k4+0][m] = vb.x; Bs[k4+1][m] = vb.y; Bs[k4+2][m] = vb.z; Bs[k4+3][m] = vb.w;
    }
    __syncthreads();
#pragma unroll
    for (int kk = 0; kk < GBK; ++kk){
      float a[2][4], b[2][4];
      *(float4*)a[0] = *(const float4*)&As[kk][ty * 4];
      *(float4*)a[1] = *(const float4*)&As[kk][64 + ty * 4];
      *(float4*)b[0] = *(const float4*)&Bs[kk][tx * 4];
      *(float4*)b[1] = *(const float4*)&Bs[kk][64 + tx * 4];
#pragma unroll
      for (int ih = 0; ih < 2; ++ih)
#pragma unroll
        for (int i = 0; i < 4; ++i)
#pragma unroll
          for (int jh = 0; jh < 2; ++jh)
#pragma unroll
            for (int j = 0; j < 4; ++j)
              acc[ih][i][jh][j] = fmaf(a[ih][i], b[jh][j], acc[ih][i][jh][j]);
    }
    __syncthreads();
  }

  float lmax = -FLT_MAX, lmin = FLT_MAX;
#pragma unroll
  for (int ih = 0; ih < 2; ++ih){
#pragma unroll
    for (int i = 0; i < 4; ++i){
      int gr = bm + ih * 64 + ty * 4 + i;
      float a = avec[gr];
#pragma unroll
      for (int jh = 0; jh < 2; ++jh){
        float dv[4];
#pragma unroll
        for (int j = 0; j < 4; ++j){
          int gc = bn + jh * 64 + tx * 4 + j;
          float t = __fadd_rn(a, hvec[gc]);                  // fl(a_b + h_k)
          float d = __fsub_rn(t, 2.0f * acc[ih][i][jh][j]);  // fl(t - 2c)
          dv[j] = d;
          lmax = fmaxf(lmax, d); lmin = fminf(lmin, d);
        }
        *(float4*)(dmat + (size_t)gr * NE + bn + jh * 64 + tx * 4) = *(float4*)&dv[0];
      }
    }
  }
  red[tid] = lmax; __syncthreads();
  for (int s = 128; s > 0; s >>= 1){ if (tid < s) red[tid] = fmaxf(red[tid], red[tid+s]); __syncthreads(); }
  float bmax = red[0];
  __syncthreads();
  red[tid] = lmin; __syncthreads();
  for (int s = 128; s > 0; s >>= 1){ if (tid < s) red[tid] = fminf(red[tid], red[tid+s]); __syncthreads(); }
  if (tid == 0){
    atomicMax(&sc32[0], f2ord(bmax));
    atomicMin(&sc32[1], f2ord(red[0]));
  }
}

// ---------------- Sinkhorn sweeps ----------------
#define EXPD(x) fexp_d((double)__fdiv_rn(__fsub_rn((x), middle), amp) * NIE)

// row step: r_k = sum_b exp(L[b,k]) * w_b ; per-k fp64 chain ascending bb within chunk.
// grid (16, 64): 1024 blocks (4/CU); 128-row chunks (fp64 reassoc only, safe)
__global__ __launch_bounds__(256) void rowPassK(const float* __restrict__ dmat, const double* __restrict__ wvec,
    const float* __restrict__ scf, double* __restrict__ partials){
  int tid = threadIdx.x;
  int k0 = blockIdx.x * 512 + tid * 2;
  int b0 = blockIdx.y * 128;
  float middle = scf[0], amp = scf[1];
  const double NIE = -(1.0 / 0.003);
  const float* p = dmat + (size_t)b0 * NE + k0;
  double a0 = 0.0, a1 = 0.0;
  if (wvec){
    for (int bb = 0; bb < 128; bb += 2){
      float2 v0 = *(const float2*)(p + (size_t)(bb+0) * NE);
      float2 v1 = *(const float2*)(p + (size_t)(bb+1) * NE);
      double w0 = wvec[b0+bb+0], w1 = wvec[b0+bb+1];
      a0 = fma(EXPD(v0.x), w0, a0); a1 = fma(EXPD(v0.y), w0, a1);
      a0 = fma(EXPD(v1.x), w1, a0); a1 = fma(EXPD(v1.y), w1, a1);
    }
  } else {
    for (int bb = 0; bb < 128; bb += 2){
      float2 v0 = *(const float2*)(p + (size_t)(bb+0) * NE);
      float2 v1 = *(const float2*)(p + (size_t)(bb+1) * NE);
      a0 += EXPD(v0.x); a1 += EXPD(v0.y);
      a0 += EXPD(v1.x); a1 += EXPD(v1.y);
    }
  }
  double* q = partials + (size_t)blockIdx.y * NE + k0;
  q[0] = a0; q[1] = a1;
}

__global__ void reduceAK(const double* __restrict__ partials, double* __restrict__ ak){
  int k = blockIdx.x * 256 + threadIdx.x;
  double s = 0.0;
  for (int c = 0; c < 64; ++c) s += partials[(size_t)c * NE + k];
  ak[k] = 1.0 / (8192.0 * s);
}

// col step: per-thread chain k = tid, tid+256, ... ascending (bit-exact)
__global__ __launch_bounds__(256) void colPassK(const float* __restrict__ dmat, const double* __restrict__ ak,
    const float* __restrict__ scf, double* __restrict__ bvec){
  __shared__ double sd[256];
  int b = blockIdx.x, tid = threadIdx.x;
  float middle = scf[0], amp = scf[1];
  const double NIE = -(1.0 / 0.003);
  const float* row = dmat + (size_t)b * NE;
  double acc = 0.0;
  for (int kb = 0; kb < 32; kb += 4){
    int k0 = tid + (kb+0) * 256, k1 = tid + (kb+1) * 256, k2 = tid + (kb+2) * 256, k3 = tid + (kb+3) * 256;
    float r0 = row[k0], r1 = row[k1], r2 = row[k2], r3 = row[k3];
    double q0 = ak[k0], q1 = ak[k1], q2 = ak[k2], q3 = ak[k3];
    acc = fma(EXPD(r0), q0, acc);
    acc = fma(EXPD(r1), q1, acc);
    acc = fma(EXPD(r2), q2, acc);
    acc = fma(EXPD(r3), q3, acc);
  }
  sd[tid] = acc; __syncthreads();
  for (int s = 128; s > 0; s >>= 1){ if (tid < s) sd[tid] += sd[tid+s]; __syncthreads(); }
  if (tid == 0) bvec[b] = 1.0 / (8192.0 * sd[0]);
}

__global__ void lnaK(const double* __restrict__ ak, double* __restrict__ lna){
  int k = blockIdx.x * 256 + threadIdx.x;
  lna[k] = log(ak[k]);
}

// argmax_k [ ln a_k + L[b,k] ] fused with loss partial for the token
__global__ __launch_bounds__(256) void argmaxLossK(const float* __restrict__ dmat, const double* __restrict__ lna,
    const float* __restrict__ scf, const float* __restrict__ X, const float* __restrict__ E,
    float* __restrict__ idxF, double* __restrict__ lparts){
  __shared__ double sv[256];
  __shared__ int    si[256];
  __shared__ int    sidx;
  int b = blockIdx.x, tid = threadIdx.x;
  float middle = scf[0], amp = scf[1];
  const double NIE = -(1.0 / 0.003);
  const float* row = dmat + (size_t)b * NE;
  double best = -1.0e300; int bk = NE;
#pragma unroll 2
  for (int c = 0; c < 8; ++c){
    int k = c * 1024 + tid * 4;
    float4 v = *(const float4*)(row + k);
    double l0 = lna[k], l1 = lna[k+1], l2 = lna[k+2], l3 = lna[k+3];
    double t0 = fma((double)__fdiv_rn(__fsub_rn(v.x, middle), amp), NIE, l0);
    double t1 = fma((double)__fdiv_rn(__fsub_rn(v.y, middle), amp), NIE, l1);
    double t2 = fma((double)__fdiv_rn(__fsub_rn(v.z, middle), amp), NIE, l2);
    double t3 = fma((double)__fdiv_rn(__fsub_rn(v.w, middle), amp), NIE, l3);
    if (t0 > best){ best = t0; bk = k; }
    if (t1 > best){ best = t1; bk = k+1; }
    if (t2 > best){ best = t2; bk = k+2; }
    if (t3 > best){ best = t3; bk = k+3; }
  }
  sv[tid] = best; si[tid] = bk; __syncthreads();
  for (int s = 128; s > 0; s >>= 1){
    if (tid < s){
      double o = sv[tid+s]; int ok = si[tid+s];
      if (o > sv[tid] || (o == sv[tid] && ok < si[tid])){ sv[tid] = o; si[tid] = ok; }
    }
    __syncthreads();
  }
  if (tid == 0){ idxF[b] = (float)si[0]; sidx = si[0]; }
  __syncthreads();

  // fused loss partial
  int id = sidx;
  const float* xr = X + (size_t)b * DIM;
  const float* er = E + (size_t)id * DIM;
  double ls = 0.0;
#pragma unroll
  for (int c = 0; c < 2; ++c){
    int dpos = tid + c * 256;
    float diff = __fsub_rn(er[dpos], xr[dpos]);
    ls = fma((double)diff, (double)diff, ls);
  }
  sv[tid] = ls; __syncthreads();
  for (int s = 128; s > 0; s >>= 1){ if (tid < s) sv[tid] += sv[tid+s]; __syncthreads(); }
  if (tid == 0) lparts[b] = sv[0];
}

__global__ __launch_bounds__(256) void lossFinK(const double* __restrict__ lparts, float* __restrict__ lossOut){
  __shared__ double sd[256];
  int tid = threadIdx.x;
  double s = 0.0;
  for (int b = tid; b < NTOK; b += 256) s += lparts[b];
  sd[tid] = s; __syncthreads();
  for (int st = 128; st > 0; st >>= 1){ if (tid < st) sd[tid] += sd[tid+st]; __syncthreads(); }
  if (tid == 0){
    double v = sd[0] / (double)((size_t)NTOK * DIM);
    float vf = (float)v;
    lossOut[0] = __fadd_rn(vf, __fmul_rn(0.25f, vf));
  }
}

__global__ __launch_bounds__(256) void out0K(const float* __restrict__ X, const float* __restrict__ E,
    const float* __restrict__ idxF, float* __restrict__ out0){
  int b = blockIdx.x, tid = threadIdx.x;
  int id = (int)idxF[b];
  const float* xr = X + (size_t)b * DIM;
  const float* er = E + (size_t)id * DIM;
#pragma unroll
  for (int c = 0; c < 2; ++c){
    int dpos = tid + c * 256;
    float xv = xr[dpos];
    float diff = __fsub_rn(er[dpos], xv);
    out0[(size_t)b * DIM + dpos] = __fadd_rn(xv, diff);
  }
}

extern "C" void kernel_launch(void* const* d_in, const int* in_sizes, int n_in,
                              void* d_out, int out_size, void* d_ws, size_t ws_size,
                              hipStream_t stream){
  (void)in_sizes; (void)n_in;
  const float* X = (const float*)d_in[0];
  const float* E = (const float*)d_in[1];
  float* out = (float*)d_out;

  if (ws_size < 268435456ull || d_ws == nullptr){
    diagK<<<2048, 256, 0, stream>>>(out, out_size, (float)(ws_size >> 20));
    return;
  }
  float* dmat = (float*)d_ws;

  // Small scratch lives in the x_q_st region of d_out (rewritten by out0K last).
  float*  avec   = out;                              // 8192 f
  float*  hvec   = out + 8192;                       // 8192 f
  double* parts  = (double*)(out + 16384);           // 64*8192 doubles (4 MB)
  double* ak     = (double*)(out + 1064960);         // 8192 d
  double* bvec   = (double*)(out + 1081344);         // 8192 d
  double* lna    = (double*)(out + 1097728);         // 8192 d
  unsigned int* sc32 = (unsigned int*)(out + 1114112);
  float*  scf    = out + 1114114;
  double* lparts = parts;

  float* out0    = out;
  float* lossOut = out + OUT0;
  float* idxF    = out + OUT0 + 1;

  initK<<<1, 64, 0, stream>>>(sc32);
  normsK<<<64, 256, 0, stream>>>(X, E, avec, hvec);

  dim3 gg(NE / GBN, NTOK / GBM);
  gemm128<<<gg, 256, 0, stream>>>(X, E, avec, hvec, dmat, sc32);
  finalizeK<<<1, 64, 0, stream>>>(sc32, scf);

  dim3 rp(16, 64);
  rowPassK<<<rp, 256, 0, stream>>>(dmat, nullptr, scf, parts);
  reduceAK<<<32, 256, 0, stream>>>(parts, ak);
  for (int it = 0; it < 4; ++it){
    colPassK<<<NTOK, 256, 0, stream>>>(dmat, ak, scf, bvec);
    rowPassK<<<rp, 256, 0, stream>>>(dmat, bvec, scf, parts);
    reduceAK<<<32, 256, 0, stream>>>(parts, ak);
  }
  // 5th col step is a per-token positive scale -> argmax invariant -> skipped

  lnaK<<<32, 256, 0, stream>>>(ak, lna);
  argmaxLossK<<<NTOK, 256, 0, stream>>>(dmat, lna, scf, X, E, idxF, lparts);
  lossFinK<<<1, 256, 0, stream>>>(lparts, lossOut);
  out0K<<<NTOK, 256, 0, stream>>>(X, E, idxF, out0);
}